// Round 3
// baseline (523.543 us; speedup 1.0000x reference)
//
#include <hip/hip_runtime.h>
#include <hip/hip_bf16.h>

// PermutationGenerator: B=8192, N=64, D=128, LATENT=256, TEMP=0.1, 20 Sinkhorn iters.
// d_in (ALL f32): [0] padded [B][64][128], [1] set_size int32 [B], [2] maskB (UNUSED),
//       [3] gumbel [B][64][64], [4] W1 [128][256], [5] b1 [256],
//       [6] W2 [256][64], [7] b2 [64]
// d_out f32: [0:8192] set_size, then permuted [B][64][128].

typedef _Float16 h16;
typedef h16 h8 __attribute__((ext_vector_type(8)));
typedef h16 h4 __attribute__((ext_vector_type(4)));
typedef float v4f __attribute__((ext_vector_type(4)));

template<int CTRL>
__device__ __forceinline__ float dppf(float x) {
  return __int_as_float(__builtin_amdgcn_update_dpp(
      0, __float_as_int(x), CTRL, 0xF, 0xF, true));
}
// sum/max over each 16-lane DPP row: quad xor1, quad xor2, row_ror:4, row_ror:8
__device__ __forceinline__ float red16_sum(float x) {
  x += dppf<0xB1>(x);    // quad_perm(1,0,3,2)
  x += dppf<0x4E>(x);    // quad_perm(2,3,0,1)
  x += dppf<0x124>(x);   // row_ror:4
  x += dppf<0x128>(x);   // row_ror:8
  return x;
}
__device__ __forceinline__ float red16_max(float x) {
  x = fmaxf(x, dppf<0xB1>(x));
  x = fmaxf(x, dppf<0x4E>(x));
  x = fmaxf(x, dppf<0x124>(x));
  x = fmaxf(x, dppf<0x128>(x));
  return x;
}
__device__ __forceinline__ float frcp(float x) { return __builtin_amdgcn_rcpf(x); }

__global__ __launch_bounds__(256) void prep_w(const float* __restrict__ W1,
                                              const float* __restrict__ W2,
                                              h16* __restrict__ w1t,
                                              h16* __restrict__ w2t) {
  int t = blockIdx.x * 256 + threadIdx.x;
  if (t < 128 * 256) {               // W1 [128][256] -> w1t [256][128]
    int kq = t >> 8, n = t & 255;
    w1t[n * 128 + kq] = (h16)W1[t];
  } else if (t < 128 * 256 + 256 * 64) {  // W2 [256][64] -> w2t [64][256]
    int t2 = t - 128 * 256;
    int kq = t2 >> 6, n = t2 & 63;
    w2t[n * 256 + kq] = (h16)W2[t2];
  }
}

// Runs LAST on the stream.
__global__ __launch_bounds__(256) void write_ss(const int* __restrict__ ssz,
                                                float* __restrict__ outp) {
  int b = blockIdx.x * 256 + threadIdx.x;
  if (b < 8192) outp[b] = (float)ssz[b];
}

// LDS layout (bytes), total 53632:
//   [0,17408)      xh   f16 [64][136]   (x, row-major, f16)
//   [17408,51456)  R1:  hh f16 [64][264] (33792)
//                    OR xth f16 [128][72] (18432, at 17408) + pth f16 [64][72] (9216, at 35840)
//                    OR outst f32 [64][133] (34048)
//   [51456,53632)  part f32 [2][4][68]
template<bool WSF>
__global__ __launch_bounds__(256) void permgen_main(
    const float* __restrict__ xf,   // f32 [B][64][128]
    const int* __restrict__ ssz,
    const float* __restrict__ gn,
    const float* __restrict__ b1,
    const float* __restrict__ b2,
    const h16* __restrict__ w1t,   // [256][128] (only if WSF)
    const h16* __restrict__ w2t,   // [64][256]  (only if WSF)
    const float* __restrict__ W1f, // [128][256] (only if !WSF)
    const float* __restrict__ W2f, // [256][64]  (only if !WSF)
    float* __restrict__ outp) {
  __shared__ __align__(16) char smem[53632];
  h16* xh = (h16*)(smem);
  h16* hh = (h16*)(smem + 17408);
  h16* xth = (h16*)(smem + 17408);
  h16* pth = (h16*)(smem + 35840);
  float* outst = (float*)(smem + 17408);
  float* part = (float*)(smem + 51456);

  const int tid = threadIdx.x;
  const int b = blockIdx.x;
  const int w = tid >> 6;
  const int lane = tid & 63;
  const int g = lane >> 4;
  const int lc = lane & 15;
  const int k = ssz[b];
  const int mcnt = (k + 15) >> 4;          // active 16-row groups
  const bool wact = (16 * w) < k;

  // ---- stage x (f32 global -> f16 LDS); keep f16 copy in regs for x^T later
  const int sr = tid >> 2, sseg = tid & 3;  // row 0..63, col-seg of 32
  h8 xv[4];
  {
    const float* src = xf + (size_t)b * 8192 + sr * 128 + sseg * 32;
#pragma unroll
    for (int v = 0; v < 4; ++v) {
      v4f d0 = *(const v4f*)(src + v * 8);
      v4f d1 = *(const v4f*)(src + v * 8 + 4);
      h8 t;
#pragma unroll
      for (int e = 0; e < 4; ++e) { t[e] = (h16)d0[e]; t[e + 4] = (h16)d1[e]; }
      xv[v] = t;
      *(h8*)&xh[sr * 136 + sseg * 32 + v * 8] = t;
    }
  }
  float b1v[4], b2v[4];
#pragma unroll
  for (int n = 0; n < 4; ++n) b1v[n] = b1[w * 64 + n * 16 + lc];
#pragma unroll
  for (int n = 0; n < 4; ++n) b2v[n] = b2[n * 16 + lc];

  __syncthreads();

  // ---- GEMM1: h = relu(x @ W1 + b1); wave w -> h cols [64w, 64w+64)
  v4f acc1[4][4];
#pragma unroll
  for (int m = 0; m < 4; ++m)
#pragma unroll
    for (int n = 0; n < 4; ++n) acc1[m][n] = (v4f){0.f, 0.f, 0.f, 0.f};
#pragma unroll
  for (int kk = 0; kk < 4; ++kk) {
    h8 av[4], bv[4];
#pragma unroll
    for (int m = 0; m < 4; ++m)
      if (m < mcnt) av[m] = *(h8*)&xh[(lc + 16 * m) * 136 + kk * 32 + g * 8];
#pragma unroll
    for (int n = 0; n < 4; ++n) {
      if (WSF) {
        bv[n] = *(const h8*)&w1t[(w * 64 + n * 16 + lc) * 128 + kk * 32 + g * 8];
      } else {
        h8 t;
#pragma unroll
        for (int e = 0; e < 8; ++e)
          t[e] = (h16)W1f[(kk * 32 + g * 8 + e) * 256 + (w * 64 + n * 16 + lc)];
        bv[n] = t;
      }
    }
#pragma unroll
    for (int m = 0; m < 4; ++m)
      if (m < mcnt)
#pragma unroll
        for (int n = 0; n < 4; ++n)
          acc1[m][n] = __builtin_amdgcn_mfma_f32_16x16x32_f16(av[m], bv[n], acc1[m][n], 0, 0, 0);
  }
#pragma unroll
  for (int m = 0; m < 4; ++m)
    if (m < mcnt)
#pragma unroll
      for (int n = 0; n < 4; ++n)
#pragma unroll
        for (int q = 0; q < 4; ++q)
          hh[(16 * m + 4 * g + q) * 264 + w * 64 + 16 * n + lc] =
              (h16)fmaxf(acc1[m][n][q] + b1v[n], 0.0f);
  __syncthreads();

  // ---- GEMM2: net = h @ W2 + b2; wave w -> net rows [16w,16w+16), all 64 cols.
  // D-frag layout == Sinkhorn ownership: thread owns rows 16w+4g+i, cols 16n+lc.
  v4f acc2[4];
#pragma unroll
  for (int n = 0; n < 4; ++n) acc2[n] = (v4f){0.f, 0.f, 0.f, 0.f};
  if (wact) {
#pragma unroll
    for (int kk = 0; kk < 8; ++kk) {
      h8 av = *(h8*)&hh[(16 * w + lc) * 264 + kk * 32 + g * 8];
#pragma unroll
      for (int n = 0; n < 4; ++n) {
        h8 bv;
        if (WSF) {
          bv = *(const h8*)&w2t[(n * 16 + lc) * 256 + kk * 32 + g * 8];
        } else {
          h8 t;
#pragma unroll
          for (int e = 0; e < 8; ++e)
            t[e] = (h16)W2f[(kk * 32 + g * 8 + e) * 64 + (n * 16 + lc)];
          bv = t;
        }
        acc2[n] = __builtin_amdgcn_mfma_f32_16x16x32_f16(av, bv, acc2[n], 0, 0, 0);
      }
    }
  }

  // ---- Sinkhorn init (exp domain): P = exp(la - rowmax), masked -> 0
  float p[4][4];
#pragma unroll
  for (int i = 0; i < 4; ++i)
#pragma unroll
    for (int n = 0; n < 4; ++n) p[i][n] = 0.0f;
  if (wact) {
#pragma unroll
    for (int i = 0; i < 4; ++i) {
      const int row = 16 * w + 4 * g + i;
      float la[4];
#pragma unroll
      for (int n = 0; n < 4; ++n) {
        const int col = 16 * n + lc;
        const bool valid = (row < k) && (col < k);
        float v = (acc2[n][i] + b2v[n] + gn[(size_t)b * 4096 + row * 64 + col]) * 10.0f;
        la[n] = valid ? v : -1e30f;
      }
      float m = fmaxf(fmaxf(la[0], la[1]), fmaxf(la[2], la[3]));
      m = red16_max(m);
#pragma unroll
      for (int n = 0; n < 4; ++n) {
        const int col = 16 * n + lc;
        const bool valid = (row < k) && (col < k);
        p[i][n] = valid ? exp2f((la[n] - m) * 1.44269504088896f) : 0.0f;
      }
    }
  }

  // ---- 20 iterations: row-normalize then col-normalize (== log-domain LSE subtract)
#pragma unroll 1
  for (int it = 0; it < 20; ++it) {
    if (wact) {
#pragma unroll
      for (int i = 0; i < 4; ++i) {  // row norm: DPP-only
        float s = (p[i][0] + p[i][1]) + (p[i][2] + p[i][3]);
        s = red16_sum(s);
        float sc = (s > 1e-37f) ? frcp(s) : 0.0f;
#pragma unroll
        for (int n = 0; n < 4; ++n) p[i][n] *= sc;
      }
      float cp[4];
#pragma unroll
      for (int n = 0; n < 4; ++n) {  // col partials over this wave's 16 rows
        float c = (p[0][n] + p[1][n]) + (p[2][n] + p[3][n]);
        c += __shfl_xor(c, 16);
        c += __shfl_xor(c, 32);
        cp[n] = c;
      }
      if (lane < 16) {
#pragma unroll
        for (int n = 0; n < 4; ++n)
          part[((it & 1) * 4 + w) * 68 + 16 * n + lc] = cp[n];
      }
    }
    __syncthreads();
    if (wact) {
#pragma unroll
      for (int n = 0; n < 4; ++n) {
        float cs = 0.0f;
#pragma unroll
        for (int pw = 0; pw < 4; ++pw)
          if (pw < mcnt) cs += part[((it & 1) * 4 + pw) * 68 + 16 * n + lc];
        float sc = (cs > 1e-37f) ? frcp(cs) : 0.0f;
#pragma unroll
        for (int i = 0; i < 4; ++i) p[i][n] *= sc;
      }
    }
  }

  // ---- stage P^T and x^T into R1 (hh is dead; all waves passed the iter barriers)
#pragma unroll
  for (int n = 0; n < 4; ++n) {
    h4 t;
#pragma unroll
    for (int i = 0; i < 4; ++i) t[i] = (h16)p[i][n];
    *(h4*)&pth[(16 * n + lc) * 72 + 16 * w + 4 * g] = t;  // P^T[col][row..row+3]
  }
#pragma unroll
  for (int v = 0; v < 4; ++v)
#pragma unroll
    for (int e = 0; e < 8; ++e)
      xth[(sseg * 32 + v * 8 + e) * 72 + sr] = xv[v][e];   // x^T[f][i]
  __syncthreads();

  // ---- GEMM3: permuted = P^T @ x; wave w -> out cols [32w, 32w+32)
  v4f acc3[4][2];
#pragma unroll
  for (int m = 0; m < 4; ++m)
#pragma unroll
    for (int nn = 0; nn < 2; ++nn) acc3[m][nn] = (v4f){0.f, 0.f, 0.f, 0.f};
  const int kkmax = (k + 31) >> 5;
#pragma unroll
  for (int kk = 0; kk < 2; ++kk) {
    if (kk < kkmax) {
      h8 av[4], bv[2];
#pragma unroll
      for (int m = 0; m < 4; ++m)
        av[m] = *(h8*)&pth[(lc + 16 * m) * 72 + kk * 32 + g * 8];
#pragma unroll
      for (int nn = 0; nn < 2; ++nn)
        bv[nn] = *(h8*)&xth[(32 * w + 16 * nn + lc) * 72 + kk * 32 + g * 8];
#pragma unroll
      for (int m = 0; m < 4; ++m)
#pragma unroll
        for (int nn = 0; nn < 2; ++nn)
          acc3[m][nn] = __builtin_amdgcn_mfma_f32_16x16x32_f16(av[m], bv[nn], acc3[m][nn], 0, 0, 0);
    }
  }
  __syncthreads();  // all GEMM3 LDS reads done before overwriting R1 with outst

#pragma unroll
  for (int m = 0; m < 4; ++m)
#pragma unroll
    for (int nn = 0; nn < 2; ++nn)
#pragma unroll
      for (int q = 0; q < 4; ++q)
        outst[(16 * m + 4 * g + q) * 133 + 32 * w + 16 * nn + lc] = acc3[m][nn][q];
  __syncthreads();

  {  // coalesced f32 store: 128 B per thread
    float* dst = outp + 8192 + (size_t)b * 8192 + sr * 128 + sseg * 32;
#pragma unroll
    for (int v = 0; v < 8; ++v)
      *(v4f*)(dst + v * 4) = *(v4f*)&outst[sr * 133 + sseg * 32 + v * 4];
  }
}

extern "C" void kernel_launch(void* const* d_in, const int* in_sizes, int n_in,
                              void* d_out, int out_size, void* d_ws, size_t ws_size,
                              hipStream_t stream) {
  const float* xf = (const float*)d_in[0];
  const int* ssz = (const int*)d_in[1];
  // d_in[2] = maskB: unused (recomputed from set_size)
  const float* gn = (const float*)d_in[3];
  const float* W1 = (const float*)d_in[4];
  const float* b1 = (const float*)d_in[5];
  const float* W2 = (const float*)d_in[6];
  const float* b2 = (const float*)d_in[7];
  float* outp = (float*)d_out;

  const size_t ws_need = (size_t)(128 * 256 + 256 * 64) * sizeof(h16);  // 98304 B
  const bool use_ws = (d_ws != nullptr) && (ws_size >= ws_need);

  if (use_ws) {
    h16* w1t = (h16*)d_ws;             // [256][128] f16
    h16* w2t = w1t + 128 * 256;        // [64][256]  f16
    prep_w<<<192, 256, 0, stream>>>(W1, W2, w1t, w2t);
    permgen_main<true><<<8192, 256, 0, stream>>>(xf, ssz, gn, b1, b2, w1t, w2t,
                                                 W1, W2, outp);
  } else {
    permgen_main<false><<<8192, 256, 0, stream>>>(xf, ssz, gn, b1, b2,
                                                  (const h16*)nullptr,
                                                  (const h16*)nullptr,
                                                  W1, W2, outp);
  }
  // set_size written LAST so nothing can clobber [0:8192).
  write_ss<<<32, 256, 0, stream>>>(ssz, outp);
}